// Round 4
// baseline (320.044 us; speedup 1.0000x reference)
//
#include <hip/hip_runtime.h>

typedef unsigned short u16;
typedef unsigned int u32;
typedef __attribute__((ext_vector_type(8))) short short8;
typedef __attribute__((ext_vector_type(4))) float f32x4;

#define NF 65536
#define KDIM 1024
#define NDIM 1024
#define NE 8
#define BM 128
#define BN 128
#define MAX_MT (NF / BM + NE)   // 520 upper bound on total m-tiles
#define GEMM_GRID (MAX_MT * 8)  // 4160, divisible by 8 (XCD swizzle valid)
#define TILE_B 16384            // one 128x64 bf16 tile = LDS image bytes
#define SORT_BLOCKS 64

#define AS1 __attribute__((address_space(1)))
#define AS3 __attribute__((address_space(3)))

__device__ __forceinline__ u16 f2bf(float f) {
  u32 u = __float_as_uint(f);
  u += 0x7FFF + ((u >> 16) & 1);  // RNE (no NaN in this data)
  return (u16)(u >> 16);
}

// 3-bit slot swizzle
__device__ __forceinline__ int swz8(int r) {
  return (r & 7) ^ ((r >> 3) & 7);
}
__device__ __forceinline__ int swz_slot(int r) { return swz8(r) << 4; }
// A-tile (fp32, 256B rows, 16 x 16B slots): 4-bit in-row slot mask.
// Per 16-lane frag group this maps 16 rows onto 16 distinct 16B slots ->
// all 32 banks exactly 2x (2-way is free, m136).
__device__ __forceinline__ int amsk(int r) {
  return (swz8(r) << 1) | (r & 1);
}

__device__ __forceinline__ void cp16(void* l, const void* g) {
  __builtin_amdgcn_global_load_lds((const AS1 unsigned int*)g,
                                   (AS3 unsigned int*)l, 16, 0, 0);
}

// ---------- deterministic (atomic-free) counting sort ----------
__global__ void k_cnt(const int* __restrict__ ids, int* __restrict__ gcnt) {
  __shared__ int wc[16][NE];
  int b = blockIdx.x, t = threadIdx.x;
  int w = t >> 6, lane = t & 63;
  if (t < 16 * NE) ((int*)wc)[t] = 0;
  __syncthreads();
  for (int s = 0; s < 4; ++s) {
    int i = (b << 10) + (s << 8) + t;
    int e = ids[i];
#pragma unroll
    for (int ee = 0; ee < NE; ++ee) {
      unsigned long long mask = __ballot(e == ee);
      if (lane == 0) wc[(s << 2) + w][ee] = (int)__popcll(mask);
    }
  }
  __syncthreads();
  if (t < NE) {
    int sum = 0;
#pragma unroll
    for (int j = 0; j < 16; ++j) sum += wc[j][t];
    gcnt[b * NE + t] = sum;
  }
}

__global__ void k_excl(const int* __restrict__ gcnt, int* __restrict__ counts,
                       int* __restrict__ offsets, int* __restrict__ tile_base,
                       int* __restrict__ base) {
  __shared__ int tot[NE], offs[NE];
  int t = threadIdx.x;
  if (t < NE) {
    int s = 0;
    for (int b = 0; b < SORT_BLOCKS; ++b) s += gcnt[b * NE + t];
    tot[t] = s;
    counts[t] = s;
  }
  __syncthreads();
  if (t == 0) {
    int run = 0, tb = 0;
    tile_base[0] = 0;
    for (int e = 0; e < NE; ++e) {
      offsets[e] = run;
      offs[e] = run;
      run += tot[e];
      tb += (tot[e] + BM - 1) / BM;
      tile_base[e + 1] = tb;
    }
  }
  __syncthreads();
  if (t < NE) {
    int run = offs[t];
    for (int b = 0; b < SORT_BLOCKS; ++b) {
      base[b * NE + t] = run;
      run += gcnt[b * NE + t];
    }
  }
}

__global__ void k_place(const int* __restrict__ ids, const int* __restrict__ base,
                        int* __restrict__ perm) {
  __shared__ int wc[16][NE], wsc[16][NE];
  int b = blockIdx.x, t = threadIdx.x;
  int w = t >> 6, lane = t & 63;
  for (int s = 0; s < 4; ++s) {
    int i = (b << 10) + (s << 8) + t;
    int e = ids[i];
#pragma unroll
    for (int ee = 0; ee < NE; ++ee) {
      unsigned long long mask = __ballot(e == ee);
      if (lane == 0) wc[(s << 2) + w][ee] = (int)__popcll(mask);
    }
  }
  __syncthreads();
  if (t < NE) {
    int run = 0;
#pragma unroll
    for (int j = 0; j < 16; ++j) {
      wsc[j][t] = run;
      run += wc[j][t];
    }
  }
  __syncthreads();
  for (int s = 0; s < 4; ++s) {
    int i = (b << 10) + (s << 8) + t;
    int e = ids[i];
#pragma unroll
    for (int ee = 0; ee < NE; ++ee) {
      unsigned long long mask = __ballot(e == ee);
      if (e == ee) {
        int rank = (int)__popcll(mask & ((1ull << lane) - 1ull));
        perm[base[b * NE + e] + wsc[(s << 2) + w][e] + rank] = i;
      }
    }
  }
}

// W[e][k][n] fp32 -> bf16 tiles [e][nt][kt][swizzled 128x64 image]
__global__ void k_wconv2(const float* __restrict__ W, u16* __restrict__ Wt) {
  int b = blockIdx.x;  // 8*8*16 = 1024 : b = (e*8+nt)*16+kt
  int e = b >> 7, nt = (b >> 4) & 7, kt = b & 15;
  int tid = threadIdx.x;
  const float* We = W + ((size_t)e << 20);
  char* dst = (char*)Wt + (size_t)b * TILE_B;
#pragma unroll
  for (int i = 0; i < 4; ++i) {
    int o = (i << 12) + (tid << 4);
    int r = o >> 7;
    int s = ((o >> 4) & 7) ^ swz8(r);
    int n = (nt << 7) + r;
    int k = (kt << 6) + (s << 3);
    u32 p[4];
#pragma unroll
    for (int j = 0; j < 4; ++j) {
      u32 lo = f2bf(We[(size_t)(k + 2 * j) * NDIM + n]);
      u32 hi = f2bf(We[(size_t)(k + 2 * j + 1) * NDIM + n]);
      p[j] = lo | (hi << 16);
    }
    *(uint4*)(dst + o) = make_uint4(p[0], p[1], p[2], p[3]);
  }
}

// ---------- fused grouped GEMM ----------
// A gathered per-lane via global_load_lds as fp32 (32KB tile, swizzled via
// pre-swizzled SOURCE, linear DMA dest); converted to bf16 at frag-read.
// B staged from pre-formatted bf16 Wt tiles. m97 2-barrier K-loop.
__global__ __launch_bounds__(256, 3) void k_gemm_fused(
    const float* __restrict__ A, const u16* __restrict__ Wt,
    const float* __restrict__ bias, const int* __restrict__ perm,
    const int* __restrict__ offsets, const int* __restrict__ counts,
    const int* __restrict__ tile_base, float* __restrict__ out) {
  int bid = blockIdx.x;
  const int cpx = GEMM_GRID >> 3;
  int l = (bid & 7) * cpx + (bid >> 3);  // XCD swizzle
  int mt = l >> 3, nt = l & 7;           // n fastest: A-panel L2 reuse
  if (mt >= tile_base[NE]) return;
  int e = 0;
#pragma unroll
  for (int ee = 0; ee < NE - 1; ++ee)
    if (mt >= tile_base[ee + 1]) e = ee + 1;
  int mloc = mt - tile_base[e];
  int row_base = offsets[e] + (mloc << 7);
  int rim = counts[e] - (mloc << 7);
  rim = rim < BM ? rim : BM;
  int n0 = nt << 7;

  __shared__ __align__(16) char ldsA[BM * 64 * 4];  // 32 KB fp32
  __shared__ __align__(16) char ldsB[BN * 64 * 2];  // 16 KB bf16

  int tid = threadIdx.x;
  int lane = tid & 63, wid = tid >> 6;
  int wr = wid >> 1, wc = wid & 1;
  int l15 = lane & 15;
  int q4 = lane >> 4;
  int lk2 = q4 << 4;

  // ---- A staging: wave wid covers rows wid*32..+31; 8 issues x 1KB.
  // DMA dest linear: o = wid*8192 + j*1024 + lane*16 -> row r=o>>8, slot
  // t'=(o>>4)&15 = lane&15. Source carries inverse swizzle: t = t'^amsk(r).
  u32 aoff[8];
#pragma unroll
  for (int j = 0; j < 8; ++j) {
    int r = (wid << 5) + (j << 2) + q4;
    int rr = r < rim ? r : rim - 1;  // dup row for pad (finite garbage, dead rows)
    int g = perm[row_base + rr];
    int t = l15 ^ amsk(r);
    aoff[j] = ((u32)g << 12) + ((u32)t << 4);
  }
  int adst = (wid << 13) + (lane << 4);
  const char* Ab = (const char*)A;

  // ---- B staging: Wt tile byte order == LDS image; 4 issues x 4KB strided.
  const char* srcB = (const char*)Wt + (size_t)(((e << 3) + nt) << 4) * TILE_B;
  int toff = tid << 4;

  // ---- frag read addresses
  // A: row r=wr*64+m*16+l15; 16B-slot t' = (q4*2) ^ amsk(r) (kk -> ^128, h -> ^16)
  int ar_addr[4];
#pragma unroll
  for (int m = 0; m < 4; ++m) {
    int r = (wr << 6) + (m << 4) + l15;
    ar_addr[m] = (r << 8) + (((q4 << 1) ^ amsk(r)) << 4);
  }
  // B: bf16 image, 128B rows, 8 slots, slot = (kslot) ^ swz8(r)
  int br_addr[4];
#pragma unroll
  for (int n = 0; n < 4; ++n) {
    int r = (wc << 6) + (n << 4) + l15;
    br_addr[n] = (r << 7) + (lk2 ^ swz_slot(r));
  }

  f32x4 acc[4][4];
#pragma unroll
  for (int m = 0; m < 4; ++m)
#pragma unroll
    for (int n = 0; n < 4; ++n) acc[m][n] = f32x4{0.f, 0.f, 0.f, 0.f};

#pragma unroll 1
  for (int kt = 0; kt < KDIM / 64; ++kt) {
    __syncthreads();  // previous compute done; LDS reusable
    u32 kb = (u32)kt << 8;  // A byte advance per K-step (64 fp32)
#pragma unroll
    for (int j = 0; j < 8; ++j)
      cp16(ldsA + adst + (j << 10), Ab + (aoff[j] + kb));
    const char* gb = srcB + ((size_t)kt << 14);
#pragma unroll
    for (int j = 0; j < 4; ++j) cp16(ldsB + toff + (j << 12), gb + toff + (j << 12));
    asm volatile("s_waitcnt vmcnt(0)" ::: "memory");
    __builtin_amdgcn_sched_barrier(0);
    __syncthreads();
#pragma unroll
    for (int kk = 0; kk < 2; ++kk) {
      short8 af[4], bfr[4];
#pragma unroll
      for (int m = 0; m < 4; ++m) {
        int a0 = ar_addr[m] ^ (kk << 7);
        f32x4 lo = *(const f32x4*)(ldsA + a0);
        f32x4 hi = *(const f32x4*)(ldsA + (a0 ^ 16));
        u32 p0 = (u32)f2bf(lo[0]) | ((u32)f2bf(lo[1]) << 16);
        u32 p1 = (u32)f2bf(lo[2]) | ((u32)f2bf(lo[3]) << 16);
        u32 p2 = (u32)f2bf(hi[0]) | ((u32)f2bf(hi[1]) << 16);
        u32 p3 = (u32)f2bf(hi[2]) | ((u32)f2bf(hi[3]) << 16);
        af[m] = __builtin_bit_cast(short8, make_uint4(p0, p1, p2, p3));
      }
#pragma unroll
      for (int n = 0; n < 4; ++n)
        bfr[n] = __builtin_bit_cast(short8,
                                    *(const uint4*)(ldsB + (br_addr[n] ^ (kk << 6))));
#pragma unroll
      for (int m = 0; m < 4; ++m)
#pragma unroll
        for (int n = 0; n < 4; ++n)
          acc[m][n] = __builtin_amdgcn_mfma_f32_16x16x32_bf16(af[m], bfr[n],
                                                              acc[m][n], 0, 0, 0);
    }
  }

  // epilogue: C row = (lane>>4)*4 + reg, col = lane&15 (m89 layout)
  float bv[4];
#pragma unroll
  for (int n = 0; n < 4; ++n)
    bv[n] = bias[(e << 10) + n0 + (wc << 6) + (n << 4) + l15];
  int rq = (lane >> 4) << 2;
#pragma unroll
  for (int m = 0; m < 4; ++m) {
#pragma unroll
    for (int j = 0; j < 4; ++j) {
      int rl = (wr << 6) + (m << 4) + rq + j;
      if (rl < rim) {
        int grow = perm[row_base + rl];
        float* orow = out + (size_t)grow * NDIM + n0 + (wc << 6) + l15;
#pragma unroll
        for (int n = 0; n < 4; ++n) orow[n << 4] = acc[m][n][j] + bv[n];
      }
    }
  }
}

// ---------------- fallback (reg-staging, strided fp32 B) ----------------
__global__ __launch_bounds__(256, 3) void k_gemm_slow(
    const float* __restrict__ A, const float* __restrict__ W,
    const float* __restrict__ bias, const int* __restrict__ perm,
    const int* __restrict__ offsets, const int* __restrict__ counts,
    const int* __restrict__ tile_base, float* __restrict__ out) {
  int bid = blockIdx.x;
  const int cpx = GEMM_GRID >> 3;
  int l = (bid & 7) * cpx + (bid >> 3);
  int mt = l >> 3, nt = l & 7;
  if (mt >= tile_base[NE]) return;
  int e = 0;
#pragma unroll
  for (int ee = 0; ee < NE - 1; ++ee)
    if (mt >= tile_base[ee + 1]) e = ee + 1;
  int mloc = mt - tile_base[e];
  int row_base = offsets[e] + (mloc << 7);
  int rim = counts[e] - (mloc << 7);
  rim = rim < BM ? rim : BM;
  int n0 = nt << 7;

  __shared__ u16 Al[BM * 64];
  __shared__ u16 Bl[BN * 64];
  char* alb = (char*)Al;
  char* blb = (char*)Bl;

  int tid = threadIdx.x;
  int lane = tid & 63, wid = tid >> 6;
  int wr = wid >> 1, wc = wid & 1;
  int l15 = lane & 15;
  int lk2 = (lane >> 4) << 4;

  int acol4 = tid & 15, argp = tid >> 4;
  const float* arow_p[8];
  int aswz[8];
#pragma unroll
  for (int i = 0; i < 8; ++i) {
    int r = argp + (i << 4);
    int rr = r < rim ? r : rim - 1;
    int grow = perm[row_base + rr];
    arow_p[i] = A + (size_t)grow * KDIM + (acol4 << 2);
    aswz[i] = r * 128 + ((acol4 << 3) ^ swz_slot(r));
  }
  int bnloc = tid & 127;
  int bkh = tid >> 7;
  const float* bcol_f = W + ((size_t)e << 20) + n0 + bnloc;
  int bswz[4];
#pragma unroll
  for (int j = 0; j < 4; ++j)
    bswz[j] = bnloc * 128 + (((bkh << 6) + (j << 4)) ^ swz_slot(bnloc));

  int ar_addr[4], br_addr[4];
#pragma unroll
  for (int m = 0; m < 4; ++m) {
    int r = (wr << 6) + (m << 4) + l15;
    ar_addr[m] = r * 128 + (lk2 ^ swz_slot(r));
  }
#pragma unroll
  for (int n = 0; n < 4; ++n) {
    int r = (wc << 6) + (n << 4) + l15;
    br_addr[n] = r * 128 + (lk2 ^ swz_slot(r));
  }

  f32x4 acc[4][4];
#pragma unroll
  for (int m = 0; m < 4; ++m)
#pragma unroll
    for (int n = 0; n < 4; ++n) acc[m][n] = f32x4{0.f, 0.f, 0.f, 0.f};

#pragma unroll 1
  for (int kt = 0; kt < KDIM / 64; ++kt) {
    int k0 = kt << 6;
    __syncthreads();
#pragma unroll
    for (int i = 0; i < 8; ++i) {
      float4 v = *(const float4*)(arow_p[i] + k0);
      u32 lo = (u32)f2bf(v.x) | ((u32)f2bf(v.y) << 16);
      u32 hi = (u32)f2bf(v.z) | ((u32)f2bf(v.w) << 16);
      *(uint2*)(alb + aswz[i]) = make_uint2(lo, hi);
    }
    float vv[32];
#pragma unroll
    for (int i = 0; i < 32; ++i)
      vv[i] = bcol_f[(size_t)(k0 + (bkh << 5) + i) << 10];
#pragma unroll
    for (int j = 0; j < 4; ++j) {
      uint4 pkt;
      pkt.x = (u32)f2bf(vv[j * 8 + 0]) | ((u32)f2bf(vv[j * 8 + 1]) << 16);
      pkt.y = (u32)f2bf(vv[j * 8 + 2]) | ((u32)f2bf(vv[j * 8 + 3]) << 16);
      pkt.z = (u32)f2bf(vv[j * 8 + 4]) | ((u32)f2bf(vv[j * 8 + 5]) << 16);
      pkt.w = (u32)f2bf(vv[j * 8 + 6]) | ((u32)f2bf(vv[j * 8 + 7]) << 16);
      *(uint4*)(blb + bswz[j]) = pkt;
    }
    __syncthreads();
#pragma unroll
    for (int kk = 0; kk < 2; ++kk) {
      int kx = kk << 6;
      short8 af[4], bfr[4];
#pragma unroll
      for (int m = 0; m < 4; ++m)
        af[m] = __builtin_bit_cast(short8, *(const uint4*)(alb + (ar_addr[m] ^ kx)));
#pragma unroll
      for (int n = 0; n < 4; ++n)
        bfr[n] = __builtin_bit_cast(short8, *(const uint4*)(blb + (br_addr[n] ^ kx)));
#pragma unroll
      for (int m = 0; m < 4; ++m)
#pragma unroll
        for (int n = 0; n < 4; ++n)
          acc[m][n] = __builtin_amdgcn_mfma_f32_16x16x32_bf16(af[m], bfr[n],
                                                              acc[m][n], 0, 0, 0);
    }
  }

  float bv[4];
#pragma unroll
  for (int n = 0; n < 4; ++n)
    bv[n] = bias[(e << 10) + n0 + (wc << 6) + (n << 4) + l15];
  int rq = (lane >> 4) << 2;
#pragma unroll
  for (int m = 0; m < 4; ++m) {
#pragma unroll
    for (int j = 0; j < 4; ++j) {
      int rl = (wr << 6) + (m << 4) + rq + j;
      if (rl < rim) {
        int grow = perm[row_base + rl];
        float* orow = out + (size_t)grow * NDIM + n0 + (wc << 6) + l15;
#pragma unroll
        for (int n = 0; n < 4; ++n) orow[n << 4] = acc[m][n][j] + bv[n];
      }
    }
  }
}

extern "C" void kernel_launch(void* const* d_in, const int* in_sizes, int n_in,
                              void* d_out, int out_size, void* d_ws,
                              size_t ws_size, hipStream_t stream) {
  const float* A = (const float*)d_in[0];
  const int* ids = (const int*)d_in[1];
  const float* W = (const float*)d_in[2];
  const float* bias = (const float*)d_in[3];
  float* out = (float*)d_out;

  char* ws = (char*)d_ws;
  int* counts = (int*)ws;            // ws+0    : 8
  int* offsets = (int*)(ws + 32);    // ws+32   : 8
  int* tile_base = (int*)(ws + 64);  // ws+64   : 9
  int* gcnt = (int*)(ws + 128);      // ws+128  : 512
  int* base = (int*)(ws + 2176);     // ws+2176 : 512
  int* perm = (int*)(ws + 8192);     // ws+8192 : 65536 ints
  const size_t wt_off = 524288;
  const size_t wt_sz = (size_t)NE * 8 * 16 * TILE_B;  // 16,777,216
  u16* Wt = (u16*)(ws + wt_off);
  bool fast = ws_size >= wt_off + wt_sz;

  k_cnt<<<SORT_BLOCKS, 256, 0, stream>>>(ids, gcnt);
  k_excl<<<1, 64, 0, stream>>>(gcnt, counts, offsets, tile_base, base);
  k_place<<<SORT_BLOCKS, 256, 0, stream>>>(ids, base, perm);
  if (fast) {
    k_wconv2<<<NE * 8 * 16, 256, 0, stream>>>(W, Wt);
    k_gemm_fused<<<GEMM_GRID, 256, 0, stream>>>(A, Wt, bias, perm, offsets,
                                                counts, tile_base, out);
  } else {
    k_gemm_slow<<<GEMM_GRID, 256, 0, stream>>>(A, W, bias, perm, offsets,
                                               counts, tile_base, out);
  }
}

// Round 5
// 297.133 us; speedup vs baseline: 1.0771x; 1.0771x over previous
//
#include <hip/hip_runtime.h>

typedef unsigned short u16;
typedef unsigned int u32;
typedef __attribute__((ext_vector_type(8))) short short8;
typedef __attribute__((ext_vector_type(4))) float f32x4;

#define NF 65536
#define KDIM 1024
#define NDIM 1024
#define NE 8
#define BM 128
#define BN 128
#define MAX_MT (NF / BM + NE)   // 520 upper bound on total m-tiles
#define GEMM_GRID (MAX_MT * 8)  // 4160, divisible by 8 (XCD swizzle valid)
#define TILE_B 16384            // one 128x64 bf16 tile = LDS image bytes
#define SORT_BLOCKS 64

#define AS1 __attribute__((address_space(1)))
#define AS3 __attribute__((address_space(3)))

__device__ __forceinline__ u16 f2bf(float f) {
  u32 u = __float_as_uint(f);
  u += 0x7FFF + ((u >> 16) & 1);  // RNE (no NaN in this data)
  return (u16)(u >> 16);
}

// 3-bit slot swizzle
__device__ __forceinline__ int swz8(int r) {
  return (r & 7) ^ ((r >> 3) & 7);
}
__device__ __forceinline__ int swz_slot(int r) { return swz8(r) << 4; }
// A-tile (fp32, 256B rows, 16 x 16B slots): 4-bit in-row slot mask.
__device__ __forceinline__ int amsk(int r) {
  return (swz8(r) << 1) | (r & 1);
}

__device__ __forceinline__ void cp16(void* l, const void* g) {
  __builtin_amdgcn_global_load_lds((const AS1 unsigned int*)g,
                                   (AS3 unsigned int*)l, 16, 0, 0);
}

// pack two f32 -> two bf16 (RNE) in one VALU op
__device__ __forceinline__ u32 cvtpk(float a, float b) {
  u32 r;
  asm("v_cvt_pk_bf16_f32 %0, %1, %2" : "=v"(r) : "v"(a), "v"(b));
  return r;
}

// ---------- deterministic (atomic-free) counting sort ----------
__global__ void k_cnt(const int* __restrict__ ids, int* __restrict__ gcnt) {
  __shared__ int wc[16][NE];
  int b = blockIdx.x, t = threadIdx.x;
  int w = t >> 6, lane = t & 63;
  if (t < 16 * NE) ((int*)wc)[t] = 0;
  __syncthreads();
  for (int s = 0; s < 4; ++s) {
    int i = (b << 10) + (s << 8) + t;
    int e = ids[i];
#pragma unroll
    for (int ee = 0; ee < NE; ++ee) {
      unsigned long long mask = __ballot(e == ee);
      if (lane == 0) wc[(s << 2) + w][ee] = (int)__popcll(mask);
    }
  }
  __syncthreads();
  if (t < NE) {
    int sum = 0;
#pragma unroll
    for (int j = 0; j < 16; ++j) sum += wc[j][t];
    gcnt[b * NE + t] = sum;
  }
}

__global__ void k_excl(const int* __restrict__ gcnt, int* __restrict__ counts,
                       int* __restrict__ offsets, int* __restrict__ tile_base,
                       int* __restrict__ base) {
  __shared__ int tot[NE], offs[NE];
  int t = threadIdx.x;
  if (t < NE) {
    int s = 0;
    for (int b = 0; b < SORT_BLOCKS; ++b) s += gcnt[b * NE + t];
    tot[t] = s;
    counts[t] = s;
  }
  __syncthreads();
  if (t == 0) {
    int run = 0, tb = 0;
    tile_base[0] = 0;
    for (int e = 0; e < NE; ++e) {
      offsets[e] = run;
      offs[e] = run;
      run += tot[e];
      tb += (tot[e] + BM - 1) / BM;
      tile_base[e + 1] = tb;
    }
  }
  __syncthreads();
  if (t < NE) {
    int run = offs[t];
    for (int b = 0; b < SORT_BLOCKS; ++b) {
      base[b * NE + t] = run;
      run += gcnt[b * NE + t];
    }
  }
}

__global__ void k_place(const int* __restrict__ ids, const int* __restrict__ base,
                        int* __restrict__ perm) {
  __shared__ int wc[16][NE], wsc[16][NE];
  int b = blockIdx.x, t = threadIdx.x;
  int w = t >> 6, lane = t & 63;
  for (int s = 0; s < 4; ++s) {
    int i = (b << 10) + (s << 8) + t;
    int e = ids[i];
#pragma unroll
    for (int ee = 0; ee < NE; ++ee) {
      unsigned long long mask = __ballot(e == ee);
      if (lane == 0) wc[(s << 2) + w][ee] = (int)__popcll(mask);
    }
  }
  __syncthreads();
  if (t < NE) {
    int run = 0;
#pragma unroll
    for (int j = 0; j < 16; ++j) {
      wsc[j][t] = run;
      run += wc[j][t];
    }
  }
  __syncthreads();
  for (int s = 0; s < 4; ++s) {
    int i = (b << 10) + (s << 8) + t;
    int e = ids[i];
#pragma unroll
    for (int ee = 0; ee < NE; ++ee) {
      unsigned long long mask = __ballot(e == ee);
      if (e == ee) {
        int rank = (int)__popcll(mask & ((1ull << lane) - 1ull));
        perm[base[b * NE + e] + wsc[(s << 2) + w][e] + rank] = i;
      }
    }
  }
}

// W[e][k][n] fp32 -> bf16 tiles [e][nt][kt][swizzled 128x64 image]
__global__ void k_wconv2(const float* __restrict__ W, u16* __restrict__ Wt) {
  int b = blockIdx.x;  // 8*8*16 = 1024 : b = (e*8+nt)*16+kt
  int e = b >> 7, nt = (b >> 4) & 7, kt = b & 15;
  int tid = threadIdx.x;
  const float* We = W + ((size_t)e << 20);
  char* dst = (char*)Wt + (size_t)b * TILE_B;
#pragma unroll
  for (int i = 0; i < 4; ++i) {
    int o = (i << 12) + (tid << 4);
    int r = o >> 7;
    int s = ((o >> 4) & 7) ^ swz8(r);
    int n = (nt << 7) + r;
    int k = (kt << 6) + (s << 3);
    u32 p[4];
#pragma unroll
    for (int j = 0; j < 4; ++j) {
      u32 lo = f2bf(We[(size_t)(k + 2 * j) * NDIM + n]);
      u32 hi = f2bf(We[(size_t)(k + 2 * j + 1) * NDIM + n]);
      p[j] = lo | (hi << 16);
    }
    *(uint4*)(dst + o) = make_uint4(p[0], p[1], p[2], p[3]);
  }
}

// ---------- fused grouped GEMM ----------
// A gathered per-lane via global_load_lds as fp32 (32KB tile, swizzled via
// pre-swizzled SOURCE, linear DMA dest); converted to bf16 at frag-read via
// v_cvt_pk_bf16_f32 (1 op / 2 elems). B staged from pre-formatted bf16 Wt.
__global__ __launch_bounds__(256, 3) void k_gemm_fused(
    const float* __restrict__ A, const u16* __restrict__ Wt,
    const float* __restrict__ bias, const int* __restrict__ perm,
    const int* __restrict__ offsets, const int* __restrict__ counts,
    const int* __restrict__ tile_base, float* __restrict__ out) {
  int bid = blockIdx.x;
  const int cpx = GEMM_GRID >> 3;
  int l = (bid & 7) * cpx + (bid >> 3);  // XCD swizzle
  int mt = l >> 3, nt = l & 7;           // n fastest: A-panel L2 reuse
  if (mt >= tile_base[NE]) return;
  int e = 0;
#pragma unroll
  for (int ee = 0; ee < NE - 1; ++ee)
    if (mt >= tile_base[ee + 1]) e = ee + 1;
  int mloc = mt - tile_base[e];
  int row_base = offsets[e] + (mloc << 7);
  int rim = counts[e] - (mloc << 7);
  rim = rim < BM ? rim : BM;
  int n0 = nt << 7;

  __shared__ __align__(16) char ldsA[BM * 64 * 4];  // 32 KB fp32
  __shared__ __align__(16) char ldsB[BN * 64 * 2];  // 16 KB bf16

  int tid = threadIdx.x;
  int lane = tid & 63, wid = tid >> 6;
  int wr = wid >> 1, wc = wid & 1;
  int l15 = lane & 15;
  int q4 = lane >> 4;
  int lk2 = q4 << 4;

  // ---- A staging: wave wid covers rows wid*32..+31; 8 issues x 1KB.
  u32 aoff[8];
#pragma unroll
  for (int j = 0; j < 8; ++j) {
    int r = (wid << 5) + (j << 2) + q4;
    int rr = r < rim ? r : rim - 1;  // dup row for pad (finite garbage, dead rows)
    int g = perm[row_base + rr];
    int t = l15 ^ amsk(r);
    aoff[j] = ((u32)g << 12) + ((u32)t << 4);
  }
  int adst = (wid << 13) + (lane << 4);
  const char* Ab = (const char*)A;

  // ---- B staging: Wt tile byte order == LDS image; 4 issues x 4KB strided.
  const char* srcB = (const char*)Wt + (size_t)(((e << 3) + nt) << 4) * TILE_B;
  int toff = tid << 4;

  // ---- frag read addresses
  int ar_addr[4];
#pragma unroll
  for (int m = 0; m < 4; ++m) {
    int r = (wr << 6) + (m << 4) + l15;
    ar_addr[m] = (r << 8) + (((q4 << 1) ^ amsk(r)) << 4);
  }
  int br_addr[4];
#pragma unroll
  for (int n = 0; n < 4; ++n) {
    int r = (wc << 6) + (n << 4) + l15;
    br_addr[n] = (r << 7) + (lk2 ^ swz_slot(r));
  }

  f32x4 acc[4][4];
#pragma unroll
  for (int m = 0; m < 4; ++m)
#pragma unroll
    for (int n = 0; n < 4; ++n) acc[m][n] = f32x4{0.f, 0.f, 0.f, 0.f};

#pragma unroll 1
  for (int kt = 0; kt < KDIM / 64; ++kt) {
    __syncthreads();  // previous compute done; LDS reusable
    u32 kb = (u32)kt << 8;  // A byte advance per K-step (64 fp32)
#pragma unroll
    for (int j = 0; j < 8; ++j)
      cp16(ldsA + adst + (j << 10), Ab + (aoff[j] + kb));
    const char* gb = srcB + ((size_t)kt << 14);
#pragma unroll
    for (int j = 0; j < 4; ++j) cp16(ldsB + toff + (j << 12), gb + toff + (j << 12));
    asm volatile("s_waitcnt vmcnt(0)" ::: "memory");
    __builtin_amdgcn_sched_barrier(0);
    __syncthreads();
#pragma unroll
    for (int kk = 0; kk < 2; ++kk) {
      short8 af[4], bfr[4];
#pragma unroll
      for (int m = 0; m < 4; ++m) {
        int a0 = ar_addr[m] ^ (kk << 7);
        f32x4 lo = *(const f32x4*)(ldsA + a0);
        f32x4 hi = *(const f32x4*)(ldsA + (a0 ^ 16));
        u32 p0 = cvtpk(lo[0], lo[1]);
        u32 p1 = cvtpk(lo[2], lo[3]);
        u32 p2 = cvtpk(hi[0], hi[1]);
        u32 p3 = cvtpk(hi[2], hi[3]);
        af[m] = __builtin_bit_cast(short8, make_uint4(p0, p1, p2, p3));
      }
#pragma unroll
      for (int n = 0; n < 4; ++n)
        bfr[n] = __builtin_bit_cast(short8,
                                    *(const uint4*)(ldsB + (br_addr[n] ^ (kk << 6))));
#pragma unroll
      for (int m = 0; m < 4; ++m)
#pragma unroll
        for (int n = 0; n < 4; ++n)
          acc[m][n] = __builtin_amdgcn_mfma_f32_16x16x32_bf16(af[m], bfr[n],
                                                              acc[m][n], 0, 0, 0);
    }
  }

  // epilogue: C row = (lane>>4)*4 + reg, col = lane&15 (m89 layout)
  float bv[4];
#pragma unroll
  for (int n = 0; n < 4; ++n)
    bv[n] = bias[(e << 10) + n0 + (wc << 6) + (n << 4) + l15];
  int rq = (lane >> 4) << 2;
#pragma unroll
  for (int m = 0; m < 4; ++m) {
#pragma unroll
    for (int j = 0; j < 4; ++j) {
      int rl = (wr << 6) + (m << 4) + rq + j;
      if (rl < rim) {
        int grow = perm[row_base + rl];
        float* orow = out + (size_t)grow * NDIM + n0 + (wc << 6) + l15;
#pragma unroll
        for (int n = 0; n < 4; ++n) orow[n << 4] = acc[m][n][j] + bv[n];
      }
    }
  }
}

// ---------------- fallback (reg-staging, strided fp32 B) ----------------
__global__ __launch_bounds__(256, 3) void k_gemm_slow(
    const float* __restrict__ A, const float* __restrict__ W,
    const float* __restrict__ bias, const int* __restrict__ perm,
    const int* __restrict__ offsets, const int* __restrict__ counts,
    const int* __restrict__ tile_base, float* __restrict__ out) {
  int bid = blockIdx.x;
  const int cpx = GEMM_GRID >> 3;
  int l = (bid & 7) * cpx + (bid >> 3);
  int mt = l >> 3, nt = l & 7;
  if (mt >= tile_base[NE]) return;
  int e = 0;
#pragma unroll
  for (int ee = 0; ee < NE - 1; ++ee)
    if (mt >= tile_base[ee + 1]) e = ee + 1;
  int mloc = mt - tile_base[e];
  int row_base = offsets[e] + (mloc << 7);
  int rim = counts[e] - (mloc << 7);
  rim = rim < BM ? rim : BM;
  int n0 = nt << 7;

  __shared__ u16 Al[BM * 64];
  __shared__ u16 Bl[BN * 64];
  char* alb = (char*)Al;
  char* blb = (char*)Bl;

  int tid = threadIdx.x;
  int lane = tid & 63, wid = tid >> 6;
  int wr = wid >> 1, wc = wid & 1;
  int l15 = lane & 15;
  int lk2 = (lane >> 4) << 4;

  int acol4 = tid & 15, argp = tid >> 4;
  const float* arow_p[8];
  int aswz[8];
#pragma unroll
  for (int i = 0; i < 8; ++i) {
    int r = argp + (i << 4);
    int rr = r < rim ? r : rim - 1;
    int grow = perm[row_base + rr];
    arow_p[i] = A + (size_t)grow * KDIM + (acol4 << 2);
    aswz[i] = r * 128 + ((acol4 << 3) ^ swz_slot(r));
  }
  int bnloc = tid & 127;
  int bkh = tid >> 7;
  const float* bcol_f = W + ((size_t)e << 20) + n0 + bnloc;
  int bswz[4];
#pragma unroll
  for (int j = 0; j < 4; ++j)
    bswz[j] = bnloc * 128 + (((bkh << 6) + (j << 4)) ^ swz_slot(bnloc));

  int ar_addr[4], br_addr[4];
#pragma unroll
  for (int m = 0; m < 4; ++m) {
    int r = (wr << 6) + (m << 4) + l15;
    ar_addr[m] = r * 128 + (lk2 ^ swz_slot(r));
  }
#pragma unroll
  for (int n = 0; n < 4; ++n) {
    int r = (wc << 6) + (n << 4) + l15;
    br_addr[n] = r * 128 + (lk2 ^ swz_slot(r));
  }

  f32x4 acc[4][4];
#pragma unroll
  for (int m = 0; m < 4; ++m)
#pragma unroll
    for (int n = 0; n < 4; ++n) acc[m][n] = f32x4{0.f, 0.f, 0.f, 0.f};

#pragma unroll 1
  for (int kt = 0; kt < KDIM / 64; ++kt) {
    int k0 = kt << 6;
    __syncthreads();
#pragma unroll
    for (int i = 0; i < 8; ++i) {
      float4 v = *(const float4*)(arow_p[i] + k0);
      u32 lo = (u32)f2bf(v.x) | ((u32)f2bf(v.y) << 16);
      u32 hi = (u32)f2bf(v.z) | ((u32)f2bf(v.w) << 16);
      *(uint2*)(alb + aswz[i]) = make_uint2(lo, hi);
    }
    float vv[32];
#pragma unroll
    for (int i = 0; i < 32; ++i)
      vv[i] = bcol_f[(size_t)(k0 + (bkh << 5) + i) << 10];
#pragma unroll
    for (int j = 0; j < 4; ++j) {
      uint4 pkt;
      pkt.x = (u32)f2bf(vv[j * 8 + 0]) | ((u32)f2bf(vv[j * 8 + 1]) << 16);
      pkt.y = (u32)f2bf(vv[j * 8 + 2]) | ((u32)f2bf(vv[j * 8 + 3]) << 16);
      pkt.z = (u32)f2bf(vv[j * 8 + 4]) | ((u32)f2bf(vv[j * 8 + 5]) << 16);
      pkt.w = (u32)f2bf(vv[j * 8 + 6]) | ((u32)f2bf(vv[j * 8 + 7]) << 16);
      *(uint4*)(blb + bswz[j]) = pkt;
    }
    __syncthreads();
#pragma unroll
    for (int kk = 0; kk < 2; ++kk) {
      int kx = kk << 6;
      short8 af[4], bfr[4];
#pragma unroll
      for (int m = 0; m < 4; ++m)
        af[m] = __builtin_bit_cast(short8, *(const uint4*)(alb + (ar_addr[m] ^ kx)));
#pragma unroll
      for (int n = 0; n < 4; ++n)
        bfr[n] = __builtin_bit_cast(short8, *(const uint4*)(blb + (br_addr[n] ^ kx)));
#pragma unroll
      for (int m = 0; m < 4; ++m)
#pragma unroll
        for (int n = 0; n < 4; ++n)
          acc[m][n] = __builtin_amdgcn_mfma_f32_16x16x32_bf16(af[m], bfr[n],
                                                              acc[m][n], 0, 0, 0);
    }
  }

  float bv[4];
#pragma unroll
  for (int n = 0; n < 4; ++n)
    bv[n] = bias[(e << 10) + n0 + (wc << 6) + (n << 4) + l15];
  int rq = (lane >> 4) << 2;
#pragma unroll
  for (int m = 0; m < 4; ++m) {
#pragma unroll
    for (int j = 0; j < 4; ++j) {
      int rl = (wr << 6) + (m << 4) + rq + j;
      if (rl < rim) {
        int grow = perm[row_base + rl];
        float* orow = out + (size_t)grow * NDIM + n0 + (wc << 6) + l15;
#pragma unroll
        for (int n = 0; n < 4; ++n) orow[n << 4] = acc[m][n][j] + bv[n];
      }
    }
  }
}

extern "C" void kernel_launch(void* const* d_in, const int* in_sizes, int n_in,
                              void* d_out, int out_size, void* d_ws,
                              size_t ws_size, hipStream_t stream) {
  const float* A = (const float*)d_in[0];
  const int* ids = (const int*)d_in[1];
  const float* W = (const float*)d_in[2];
  const float* bias = (const float*)d_in[3];
  float* out = (float*)d_out;

  char* ws = (char*)d_ws;
  int* counts = (int*)ws;            // ws+0    : 8
  int* offsets = (int*)(ws + 32);    // ws+32   : 8
  int* tile_base = (int*)(ws + 64);  // ws+64   : 9
  int* gcnt = (int*)(ws + 128);      // ws+128  : 512
  int* base = (int*)(ws + 2176);     // ws+2176 : 512
  int* perm = (int*)(ws + 8192);     // ws+8192 : 65536 ints
  const size_t wt_off = 524288;
  const size_t wt_sz = (size_t)NE * 8 * 16 * TILE_B;  // 16,777,216
  u16* Wt = (u16*)(ws + wt_off);
  bool fast = ws_size >= wt_off + wt_sz;

  k_cnt<<<SORT_BLOCKS, 256, 0, stream>>>(ids, gcnt);
  k_excl<<<1, 64, 0, stream>>>(gcnt, counts, offsets, tile_base, base);
  k_place<<<SORT_BLOCKS, 256, 0, stream>>>(ids, base, perm);
  if (fast) {
    k_wconv2<<<NE * 8 * 16, 256, 0, stream>>>(W, Wt);
    k_gemm_fused<<<GEMM_GRID, 256, 0, stream>>>(A, Wt, bias, perm, offsets,
                                                counts, tile_base, out);
  } else {
    k_gemm_slow<<<GEMM_GRID, 256, 0, stream>>>(A, W, bias, perm, offsets,
                                               counts, tile_base, out);
  }
}